// Round 1
// baseline (1730.654 us; speedup 1.0000x reference)
//
#include <hip/hip_runtime.h>

typedef unsigned short u16;
typedef unsigned int u32;

using short8 = __attribute__((ext_vector_type(8))) short;
using f32x4  = __attribute__((ext_vector_type(4))) float;

constexpr int kB = 2, kT = 2048, kD = 2048, kH = 16, kK = 128, kV = 128;
constexpr int kM  = kB * kT;   // 4096 tokens
constexpr int kHK = kH * kK;   // 2048
constexpr int kHV = kH * kV;   // 2048

// ---------------- workspace layout (bytes). Overlays are deliberate. -------
constexpr size_t OFF_XB    = 0;          // bf16 x            16777216
constexpr size_t OFF_WQB   = 16777216;   // bf16 Wq            8388608
constexpr size_t OFF_WKB   = 25165824;   // bf16 Wk            8388608
constexpr size_t OFF_QC    = 0;          // f32 qc [B,H,T,K]  33554432 (aliases xb+Wqb+Wkb, dead by then)
constexpr size_t OFF_WVB   = 33554432;   // bf16 Wv            8388608
constexpr size_t OFF_WF1B  = 41943040;   // bf16 Wf1            524288
constexpr size_t OFF_WG1B  = 42467328;   // bf16 Wg1            524288
constexpr size_t OFF_WF2B  = 42991616;   // bf16 Wf2            524288
constexpr size_t OFF_WG2B  = 43515904;   // bf16 Wg2            524288
constexpr size_t OFF_WBP   = 44040192;   // bf16 Wb padded to [128,2048] 524288
constexpr size_t OFF_F1B   = 44564480;   // bf16 f1 [4096,128] 1048576
constexpr size_t OFF_G1B   = 45613056;   // bf16 g1 [4096,128] 1048576
constexpr size_t OFF_BRAW  = 46661632;   // f32 braw [4096,128] 2097152
constexpr size_t OFF_QRAW  = 48758784;   // bf16 qraw          16777216
constexpr size_t OFF_KRAW  = 65536000;   // bf16 kraw          16777216
constexpr size_t OFF_YF    = 48758784;   // f32 y [B,H,T,V]    33554432 (aliases qraw+kraw, dead by then)
constexpr size_t OFF_VRAW  = 82313216;   // bf16 vraw          16777216
constexpr size_t OFF_YGB   = 82313216;   // bf16 yg            16777216 (aliases vraw, dead by then)
constexpr size_t OFF_GRAW  = 99090432;   // bf16 g_raw         16777216
constexpr size_t OFF_GATEB = 115867648;  // bf16 gate          16777216
constexpr size_t OFF_WOUTB = 132644864;  // bf16 Wout           8388608
constexpr size_t OFF_KC    = 141033472;  // f32 kc             33554432
constexpr size_t OFF_VC    = 174587904;  // f32 vc             33554432
constexpr size_t OFF_DEC   = 208142336;  // f32 decay          33554432
constexpr size_t OFF_BETA  = 241696768;  // f32 beta [B,H,T]     262144
// total need: 241958912 bytes (~231 MB)

// ---------------- small helpers ----------------
__device__ __forceinline__ u16 f2bf(float f) {
  union { float f; u32 u; } a; a.f = f;
  u32 u = a.u;
  u += 0x7fffu + ((u >> 16) & 1u);   // round-to-nearest-even
  return (u16)(u >> 16);
}
__device__ __forceinline__ float bflo(u32 u) {
  union { u32 u; float f; } a; a.u = u << 16; return a.f;
}
__device__ __forceinline__ float bfhi(u32 u) {
  union { u32 u; float f; } a; a.u = u & 0xffff0000u; return a.f;
}
__device__ __forceinline__ float sigmoidf(float x) { return 1.0f / (1.0f + expf(-x)); }

#define GL_AS1 __attribute__((address_space(1)))
#define GL_AS3 __attribute__((address_space(3)))
// async global->LDS, 16B per lane. LDS dest must be wave-uniform-base + lane*16.
__device__ __forceinline__ void async_lds16(const void* g, void* l) {
  __builtin_amdgcn_global_load_lds((GL_AS1 u32*)(size_t)g,
                                   (GL_AS3 u32*)(u32)(size_t)l, 16, 0, 0);
}

// ---------------- cast / pad kernels ----------------
__global__ __launch_bounds__(256) void cast_bf16(const float* __restrict__ in,
                                                 u16* __restrict__ out, int n) {
  int i = (blockIdx.x * 256 + threadIdx.x) * 4;
  if (i >= n) return;
  float4 v = *(const float4*)(in + i);
  uint2 st;
  st.x = (u32)f2bf(v.x) | ((u32)f2bf(v.y) << 16);
  st.y = (u32)f2bf(v.z) | ((u32)f2bf(v.w) << 16);
  *(uint2*)(out + i) = st;
}

// Wb [16,2048] f32 -> [128,2048] bf16 zero-padded
__global__ __launch_bounds__(256) void pad_wb(const float* __restrict__ Wb,
                                              u16* __restrict__ out) {
  int i = (blockIdx.x * 256 + threadIdx.x) * 4;  // < 262144
  int row = i >> 11;
  uint2 st; st.x = 0; st.y = 0;
  if (row < 16) {
    float4 v = *(const float4*)(Wb + i);
    st.x = (u32)f2bf(v.x) | ((u32)f2bf(v.y) << 16);
    st.y = (u32)f2bf(v.z) | ((u32)f2bf(v.w) << 16);
  }
  *(uint2*)(out + i) = st;
}

// ---------------- bf16 MFMA GEMM:  C[m,n] = sum_k A[m,k] * B[n,k] ----------
// A: [M,K] bf16 row-major, B: [N,K] bf16 row-major. M%128==0, N%128==0, K%32==0.
template <bool BF16OUT>
__global__ __launch_bounds__(256) void gemm_bt(const u16* __restrict__ A,
                                               const u16* __restrict__ B,
                                               void* __restrict__ Cout,
                                               int M, int N, int K) {
  __shared__ u16 As[128 * 32];
  __shared__ u16 Bs[128 * 32];
  const int tid  = threadIdx.x;
  const int lane = tid & 63;
  const int wave = tid >> 6;
  const int wm = (wave >> 1) * 64;
  const int wn = (wave & 1) * 64;
  const long row0 = (long)blockIdx.x * 128;
  const long col0 = (long)blockIdx.y * 128;
  const int srow = tid >> 2;
  const int scol = (tid & 3) * 8;
  const u16* aptr = A + (row0 + srow) * (size_t)K + scol;
  const u16* bptr = B + (col0 + srow) * (size_t)K + scol;
  u16* asd  = &As[tid * 8];
  u16* asd2 = &As[2048 + tid * 8];
  u16* bsd  = &Bs[tid * 8];
  u16* bsd2 = &Bs[2048 + tid * 8];
  const int mrow = lane & 15;
  const int kq = (lane >> 4) * 8;
  f32x4 acc[4][4] = {};
  for (int k0 = 0; k0 < K; k0 += 32) {
    async_lds16(aptr, asd);
    async_lds16(aptr + (size_t)64 * K, asd2);
    async_lds16(bptr, bsd);
    async_lds16(bptr + (size_t)64 * K, bsd2);
    aptr += 32; bptr += 32;
    __syncthreads();   // drains vmcnt -> staged data visible
    short8 af[4], bfr[4];
#pragma unroll
    for (int i = 0; i < 4; ++i)
      af[i] = *(const short8*)(&As[(wm + i * 16 + mrow) * 32 + kq]);
#pragma unroll
    for (int j = 0; j < 4; ++j)
      bfr[j] = *(const short8*)(&Bs[(wn + j * 16 + mrow) * 32 + kq]);
#pragma unroll
    for (int i = 0; i < 4; ++i)
#pragma unroll
      for (int j = 0; j < 4; ++j)
        acc[i][j] = __builtin_amdgcn_mfma_f32_16x16x32_bf16(af[i], bfr[j], acc[i][j], 0, 0, 0);
    __syncthreads();   // all ds_reads done before next staging overwrites
  }
  const int cn = lane & 15;
  const int rq = (lane >> 4) * 4;
#pragma unroll
  for (int i = 0; i < 4; ++i)
#pragma unroll
    for (int j = 0; j < 4; ++j) {
      size_t r = (size_t)(row0 + wm + i * 16 + rq);
      size_t c = (size_t)(col0 + wn + j * 16 + cn);
#pragma unroll
      for (int rr = 0; rr < 4; ++rr) {
        if constexpr (BF16OUT)
          ((u16*)Cout)[(r + rr) * N + c] = f2bf(acc[i][j][rr]);
        else
          ((float*)Cout)[(r + rr) * N + c] = acc[i][j][rr];
      }
    }
}

// ---------------- conv(4-tap causal) + silu + l2norm + decay + beta --------
// one wave per (b,t,h); lane handles channels 2*lane, 2*lane+1
__global__ __launch_bounds__(256) void convprep(
    const u16* __restrict__ qraw, const u16* __restrict__ kraw,
    const u16* __restrict__ vraw, const u16* __restrict__ graw,
    const float* __restrict__ braw,
    const float* __restrict__ qcw, const float* __restrict__ kcw,
    const float* __restrict__ vcw, const float* __restrict__ A_log,
    const float* __restrict__ dt_bias,
    float* __restrict__ qc, float* __restrict__ kc, float* __restrict__ vc,
    float* __restrict__ dec, float* __restrict__ beta) {
  const int wid  = blockIdx.x * 4 + (threadIdx.x >> 6);
  const int lane = threadIdx.x & 63;
  const int h  = wid & 15;
  const int bt = wid >> 4;        // b*T + t
  const int t  = bt & (kT - 1);
  const int b  = bt >> 11;
  const int c0 = lane * 2;
  const size_t colofs = (size_t)h * kK + c0;
  const size_t rowb = (size_t)bt * kHK + colofs;
  const float* wq = qcw + colofs * 4;
  const float* wk = kcw + colofs * 4;
  const float* wv = vcw + colofs * 4;
  float qa0 = 0, qa1 = 0, ka0 = 0, ka1 = 0, va0 = 0, va1 = 0;
#pragma unroll
  for (int i = 0; i < 4; ++i) {       // tap i multiplies x[t-3+i]
    int tt = t - 3 + i;
    if (tt >= 0) {
      size_t ro = rowb - (size_t)(3 - i) * kHK;
      u32 uq = *(const u32*)(qraw + ro);
      u32 uk = *(const u32*)(kraw + ro);
      u32 uv = *(const u32*)(vraw + ro);
      qa0 += bflo(uq) * wq[i];  qa1 += bfhi(uq) * wq[4 + i];
      ka0 += bflo(uk) * wk[i];  ka1 += bfhi(uk) * wk[4 + i];
      va0 += bflo(uv) * wv[i];  va1 += bfhi(uv) * wv[4 + i];
    }
  }
  qa0 *= sigmoidf(qa0); qa1 *= sigmoidf(qa1);
  ka0 *= sigmoidf(ka0); ka1 *= sigmoidf(ka1);
  va0 *= sigmoidf(va0); va1 *= sigmoidf(va1);
  float sq = qa0 * qa0 + qa1 * qa1;
  float sk = ka0 * ka0 + ka1 * ka1;
#pragma unroll
  for (int m = 1; m < 64; m <<= 1) {
    sq += __shfl_xor(sq, m);
    sk += __shfl_xor(sk, m);
  }
  float qinv = 1.0f / fmaxf(sqrtf(sq), 1e-12f);
  float kinv = 1.0f / fmaxf(sqrtf(sk), 1e-12f);
  const size_t outb = ((size_t)(b * kH + h) * kT + t) * kK + c0;
  *(float2*)(qc + outb) = make_float2(qa0 * qinv, qa1 * qinv);
  *(float2*)(kc + outb) = make_float2(ka0 * kinv, ka1 * kinv);
  *(float2*)(vc + outb) = make_float2(va0, va1);
  // decay = exp(-exp(A_log)*softplus(g_raw + dt_bias))
  u32 ug = *(const u32*)(graw + rowb);
  float Ae = expf(A_log[h]);
  float g0 = bflo(ug) + dt_bias[colofs];
  float g1 = bfhi(ug) + dt_bias[colofs + 1];
  float sp0 = (g0 > 15.f) ? g0 : log1pf(expf(g0));
  float sp1 = (g1 > 15.f) ? g1 : log1pf(expf(g1));
  *(float2*)(dec + outb) = make_float2(expf(-Ae * sp0), expf(-Ae * sp1));
  if (lane == 0) {
    float bv = braw[(size_t)bt * 128 + h];
    beta[(size_t)(b * kH + h) * kT + t] = sigmoidf(bv);
  }
}

// ---------------- KDA delta-rule scan ----------------
// wave per (bh, vgroup of 4 v-cols). lane = kg*4+vcl, kg in [0,16): 8 k-rows.
__global__ __launch_bounds__(256) void kda_scan(
    const float* __restrict__ qc, const float* __restrict__ kc,
    const float* __restrict__ vcp, const float* __restrict__ dec,
    const float* __restrict__ betap, float* __restrict__ yf) {
  const int wid  = blockIdx.x * 4 + (threadIdx.x >> 6);
  const int lane = threadIdx.x & 63;
  const int bh = wid >> 5;
  const int vg = wid & 31;
  const int vcl = lane & 3;
  const int kg = lane >> 2;
  const int vi = vg * 4 + vcl;
  const size_t base  = (size_t)bh * kT * kK + kg * 8;
  const size_t vbase = (size_t)bh * kT * kV + vi;
  const size_t ybase = (size_t)bh * kT * kV + vi;
  const float* bp = betap + (size_t)bh * kT;
  float S0 = 0, S1 = 0, S2 = 0, S3 = 0, S4 = 0, S5 = 0, S6 = 0, S7 = 0;
  float4 q0 = *(const float4*)(qc + base);
  float4 q1 = *(const float4*)(qc + base + 4);
  float4 kk0 = *(const float4*)(kc + base);
  float4 kk1 = *(const float4*)(kc + base + 4);
  float4 d0 = *(const float4*)(dec + base);
  float4 d1 = *(const float4*)(dec + base + 4);
  float vt = vcp[vbase];
  float bt = bp[0];
  for (int t = 0; t < kT; ++t) {
    const int tn = (t < kT - 1) ? t + 1 : t;
    const size_t nb = base + (size_t)tn * kK;
    float4 nq0 = *(const float4*)(qc + nb);
    float4 nq1 = *(const float4*)(qc + nb + 4);
    float4 nk0 = *(const float4*)(kc + nb);
    float4 nk1 = *(const float4*)(kc + nb + 4);
    float4 nd0 = *(const float4*)(dec + nb);
    float4 nd1 = *(const float4*)(dec + nb + 4);
    float nvt = vcp[vbase + (size_t)tn * kV];
    float nbt = bp[tn];
    // S' = decay*S ; err = v - k.S' ; S = S' + beta*err*k ; o = q.S
    float t0 = d0.x * S0, t1 = d0.y * S1, t2 = d0.z * S2, t3 = d0.w * S3;
    float t4 = d1.x * S4, t5 = d1.y * S5, t6 = d1.z * S6, t7 = d1.w * S7;
    float dot = ((kk0.x * t0 + kk0.y * t1) + (kk0.z * t2 + kk0.w * t3)) +
                ((kk1.x * t4 + kk1.y * t5) + (kk1.z * t6 + kk1.w * t7));
    dot += __shfl_xor(dot, 4);
    dot += __shfl_xor(dot, 8);
    dot += __shfl_xor(dot, 16);
    dot += __shfl_xor(dot, 32);
    float u = bt * (vt - dot);
    S0 = fmaf(u, kk0.x, t0); S1 = fmaf(u, kk0.y, t1);
    S2 = fmaf(u, kk0.z, t2); S3 = fmaf(u, kk0.w, t3);
    S4 = fmaf(u, kk1.x, t4); S5 = fmaf(u, kk1.y, t5);
    S6 = fmaf(u, kk1.z, t6); S7 = fmaf(u, kk1.w, t7);
    float o = ((q0.x * S0 + q0.y * S1) + (q0.z * S2 + q0.w * S3)) +
              ((q1.x * S4 + q1.y * S5) + (q1.z * S6 + q1.w * S7));
    o += __shfl_xor(o, 4);
    o += __shfl_xor(o, 8);
    o += __shfl_xor(o, 16);
    o += __shfl_xor(o, 32);
    if (kg == 0) yf[ybase + (size_t)t * kV] = o;
    q0 = nq0; q1 = nq1; kk0 = nk0; kk1 = nk1; d0 = nd0; d1 = nd1;
    vt = nvt; bt = nbt;
  }
}

// ---------------- rmsnorm * o_norm_w * sigmoid(gate+bg) -> bf16 -----------
__global__ __launch_bounds__(256) void postk(
    const float* __restrict__ yf, const u16* __restrict__ gateb,
    const float* __restrict__ bg, const float* __restrict__ onw,
    u16* __restrict__ ygb) {
  const int wid  = blockIdx.x * 4 + (threadIdx.x >> 6);
  const int lane = threadIdx.x & 63;
  const int h  = wid & 15;
  const int bt = wid >> 4;
  const int t  = bt & (kT - 1);
  const int b  = bt >> 11;
  const int v0 = lane * 2;
  const size_t yi = ((size_t)(b * kH + h) * kT + t) * kV + v0;
  float2 yv = *(const float2*)(yf + yi);
  float s = yv.x * yv.x + yv.y * yv.y;
#pragma unroll
  for (int m = 1; m < 64; m <<= 1) s += __shfl_xor(s, m);
  float scale = rsqrtf(s * (1.0f / 128.0f) + 1.1920929e-07f);
  const size_t gi = (size_t)bt * kHV + (size_t)h * kV + v0;
  u32 ug = *(const u32*)(gateb + gi);
  float g0 = bflo(ug) + bg[h * kV + v0];
  float g1 = bfhi(ug) + bg[h * kV + v0 + 1];
  float r0 = yv.x * scale * onw[v0] * sigmoidf(g0);
  float r1 = yv.y * scale * onw[v0 + 1] * sigmoidf(g1);
  *(u32*)(ygb + gi) = (u32)f2bf(r0) | ((u32)f2bf(r1) << 16);
}

// ---------------- host launcher ----------------
extern "C" void kernel_launch(void* const* d_in, const int* in_sizes, int n_in,
                              void* d_out, int out_size, void* d_ws, size_t ws_size,
                              hipStream_t stream) {
  (void)in_sizes; (void)n_in; (void)out_size; (void)ws_size;
  const float* x    = (const float*)d_in[0];
  const float* Wq   = (const float*)d_in[1];
  const float* Wk   = (const float*)d_in[2];
  const float* Wv   = (const float*)d_in[3];
  const float* Wf1  = (const float*)d_in[4];
  const float* Wf2  = (const float*)d_in[5];
  const float* Wb   = (const float*)d_in[6];
  const float* Wg1  = (const float*)d_in[7];
  const float* Wg2  = (const float*)d_in[8];
  const float* bg   = (const float*)d_in[9];
  const float* onw  = (const float*)d_in[10];
  const float* Wout = (const float*)d_in[11];
  const float* A_log   = (const float*)d_in[12];
  const float* dt_bias = (const float*)d_in[13];
  const float* qcw  = (const float*)d_in[14];
  const float* kcw  = (const float*)d_in[15];
  const float* vcw  = (const float*)d_in[16];

  char* ws = (char*)d_ws;
  u16* xb    = (u16*)(ws + OFF_XB);
  u16* Wqb   = (u16*)(ws + OFF_WQB);
  u16* Wkb   = (u16*)(ws + OFF_WKB);
  u16* Wvb   = (u16*)(ws + OFF_WVB);
  u16* Wf1b  = (u16*)(ws + OFF_WF1B);
  u16* Wg1b  = (u16*)(ws + OFF_WG1B);
  u16* Wf2b  = (u16*)(ws + OFF_WF2B);
  u16* Wg2b  = (u16*)(ws + OFF_WG2B);
  u16* Wbp   = (u16*)(ws + OFF_WBP);
  u16* Woutb = (u16*)(ws + OFF_WOUTB);
  u16* qraw  = (u16*)(ws + OFF_QRAW);
  u16* kraw  = (u16*)(ws + OFF_KRAW);
  u16* vraw  = (u16*)(ws + OFF_VRAW);
  u16* graw  = (u16*)(ws + OFF_GRAW);
  u16* gateb = (u16*)(ws + OFF_GATEB);
  u16* f1b   = (u16*)(ws + OFF_F1B);
  u16* g1b   = (u16*)(ws + OFF_G1B);
  u16* ygb   = (u16*)(ws + OFF_YGB);
  float* brawf = (float*)(ws + OFF_BRAW);
  float* qcf   = (float*)(ws + OFF_QC);
  float* kcf   = (float*)(ws + OFF_KC);
  float* vcf   = (float*)(ws + OFF_VC);
  float* decf  = (float*)(ws + OFF_DEC);
  float* betaf = (float*)(ws + OFF_BETA);
  float* yff   = (float*)(ws + OFF_YF);

  auto cast = [&](const float* src, u16* dst, int n) {
    cast_bf16<<<(n / 4 + 255) / 256, 256, 0, stream>>>(src, dst, n);
  };
  cast(x, xb, kM * kD);
  cast(Wq, Wqb, kHK * kD);
  cast(Wk, Wkb, kHK * kD);
  cast(Wv, Wvb, kHV * kD);
  cast(Wout, Woutb, kD * kHV);
  cast(Wf1, Wf1b, kV * kD);
  cast(Wg1, Wg1b, kV * kD);
  cast(Wf2, Wf2b, kHK * kV);
  cast(Wg2, Wg2b, kHV * kV);
  pad_wb<<<(128 * 2048 / 4 + 255) / 256, 256, 0, stream>>>(Wb, Wbp);

  dim3 blk(256);
  gemm_bt<true><<<dim3(kM / 128, kHK / 128), blk, 0, stream>>>(xb, Wqb, qraw, kM, kHK, kD);
  gemm_bt<true><<<dim3(kM / 128, kHK / 128), blk, 0, stream>>>(xb, Wkb, kraw, kM, kHK, kD);
  gemm_bt<true><<<dim3(kM / 128, kHV / 128), blk, 0, stream>>>(xb, Wvb, vraw, kM, kHV, kD);
  gemm_bt<true><<<dim3(kM / 128, 1), blk, 0, stream>>>(xb, Wf1b, f1b, kM, 128, kD);
  gemm_bt<true><<<dim3(kM / 128, 1), blk, 0, stream>>>(xb, Wg1b, g1b, kM, 128, kD);
  gemm_bt<false><<<dim3(kM / 128, 1), blk, 0, stream>>>(xb, Wbp, brawf, kM, 128, kD);
  gemm_bt<true><<<dim3(kM / 128, kHK / 128), blk, 0, stream>>>(f1b, Wf2b, graw, kM, kHK, kV);
  gemm_bt<true><<<dim3(kM / 128, kHV / 128), blk, 0, stream>>>(g1b, Wg2b, gateb, kM, kHV, kV);

  convprep<<<kB * kT * kH / 4, 256, 0, stream>>>(qraw, kraw, vraw, graw, brawf,
                                                 qcw, kcw, vcw, A_log, dt_bias,
                                                 qcf, kcf, vcf, decf, betaf);

  kda_scan<<<kB * kH * 32 / 4, 256, 0, stream>>>(qcf, kcf, vcf, decf, betaf, yff);

  postk<<<kB * kT * kH / 4, 256, 0, stream>>>(yff, gateb, bg, onw, ygb);

  gemm_bt<false><<<dim3(kM / 128, kD / 128), blk, 0, stream>>>(ygb, Woutb, (float*)d_out, kM, kD, kHV);
}

// Round 2
// 1567.003 us; speedup vs baseline: 1.1044x; 1.1044x over previous
//
#include <hip/hip_runtime.h>

typedef unsigned short u16;
typedef unsigned int u32;

using short8 = __attribute__((ext_vector_type(8))) short;
using f32x4  = __attribute__((ext_vector_type(4))) float;

constexpr int kB = 2, kT = 2048, kD = 2048, kH = 16, kK = 128, kV = 128;
constexpr int kM  = kB * kT;   // 4096 tokens
constexpr int kHK = kH * kK;   // 2048
constexpr int kHV = kH * kV;   // 2048

// ---------------- workspace layout (bytes). Overlays are deliberate. -------
constexpr size_t OFF_XB    = 0;          // bf16 x            16777216
constexpr size_t OFF_WQB   = 16777216;   // bf16 Wq            8388608
constexpr size_t OFF_WKB   = 25165824;   // bf16 Wk            8388608
constexpr size_t OFF_QC    = 0;          // f32 qc [B,H,T,K]  33554432 (aliases xb+Wqb+Wkb, dead by then)
constexpr size_t OFF_WVB   = 33554432;   // bf16 Wv            8388608
constexpr size_t OFF_WF1B  = 41943040;   // bf16 Wf1            524288
constexpr size_t OFF_WG1B  = 42467328;   // bf16 Wg1            524288
constexpr size_t OFF_WF2B  = 42991616;   // bf16 Wf2            524288
constexpr size_t OFF_WG2B  = 43515904;   // bf16 Wg2            524288
constexpr size_t OFF_WBP   = 44040192;   // bf16 Wb padded to [128,2048] 524288
constexpr size_t OFF_F1B   = 44564480;   // bf16 f1 [4096,128] 1048576
constexpr size_t OFF_G1B   = 45613056;   // bf16 g1 [4096,128] 1048576
constexpr size_t OFF_BRAW  = 46661632;   // f32 braw [4096,128] 2097152
constexpr size_t OFF_QRAW  = 48758784;   // bf16 qraw          16777216
constexpr size_t OFF_KRAW  = 65536000;   // bf16 kraw          16777216
constexpr size_t OFF_YF    = 48758784;   // f32 y [B,H,T,V]    33554432 (aliases qraw+kraw, dead by then)
constexpr size_t OFF_VRAW  = 82313216;   // bf16 vraw          16777216
constexpr size_t OFF_YGB   = 82313216;   // bf16 yg            16777216 (aliases vraw, dead by then)
constexpr size_t OFF_GRAW  = 99090432;   // bf16 g_raw         16777216
constexpr size_t OFF_GATEB = 115867648;  // bf16 gate          16777216
constexpr size_t OFF_WOUTB = 132644864;  // bf16 Wout           8388608
constexpr size_t OFF_KC    = 141033472;  // f32 kc             33554432
constexpr size_t OFF_VC    = 174587904;  // f32 vc             33554432
constexpr size_t OFF_DEC   = 208142336;  // f32 decay          33554432
constexpr size_t OFF_BETA  = 241696768;  // f32 beta [B,H,T]     262144
// total need: 241958912 bytes (~231 MB)

// ---------------- small helpers ----------------
__device__ __forceinline__ u16 f2bf(float f) {
  union { float f; u32 u; } a; a.f = f;
  u32 u = a.u;
  u += 0x7fffu + ((u >> 16) & 1u);   // round-to-nearest-even
  return (u16)(u >> 16);
}
__device__ __forceinline__ float bflo(u32 u) {
  union { u32 u; float f; } a; a.u = u << 16; return a.f;
}
__device__ __forceinline__ float bfhi(u32 u) {
  union { u32 u; float f; } a; a.u = u & 0xffff0000u; return a.f;
}
__device__ __forceinline__ float sigmoidf(float x) { return 1.0f / (1.0f + expf(-x)); }

#define GL_AS1 __attribute__((address_space(1)))
#define GL_AS3 __attribute__((address_space(3)))
// async global->LDS, 16B per lane. LDS dest must be wave-uniform-base + lane*16.
__device__ __forceinline__ void async_lds16(const void* g, void* l) {
  __builtin_amdgcn_global_load_lds((GL_AS1 u32*)(size_t)g,
                                   (GL_AS3 u32*)(u32)(size_t)l, 16, 0, 0);
}

// ---------------- cast / pad kernels ----------------
__global__ __launch_bounds__(256) void cast_bf16(const float* __restrict__ in,
                                                 u16* __restrict__ out, int n) {
  int i = (blockIdx.x * 256 + threadIdx.x) * 4;
  if (i >= n) return;
  float4 v = *(const float4*)(in + i);
  uint2 st;
  st.x = (u32)f2bf(v.x) | ((u32)f2bf(v.y) << 16);
  st.y = (u32)f2bf(v.z) | ((u32)f2bf(v.w) << 16);
  *(uint2*)(out + i) = st;
}

// Wb [16,2048] f32 -> [128,2048] bf16 zero-padded
__global__ __launch_bounds__(256) void pad_wb(const float* __restrict__ Wb,
                                              u16* __restrict__ out) {
  int i = (blockIdx.x * 256 + threadIdx.x) * 4;  // < 262144
  int row = i >> 11;
  uint2 st; st.x = 0; st.y = 0;
  if (row < 16) {
    float4 v = *(const float4*)(Wb + i);
    st.x = (u32)f2bf(v.x) | ((u32)f2bf(v.y) << 16);
    st.y = (u32)f2bf(v.z) | ((u32)f2bf(v.w) << 16);
  }
  *(uint2*)(out + i) = st;
}

// ---------------- bf16 MFMA GEMM:  C[m,n] = sum_k A[m,k] * B[n,k] ----------
// A: [M,K] bf16 row-major, B: [N,K] bf16 row-major. M%128==0, N%128==0, K%32==0.
template <bool BF16OUT>
__global__ __launch_bounds__(256) void gemm_bt(const u16* __restrict__ A,
                                               const u16* __restrict__ B,
                                               void* __restrict__ Cout,
                                               int M, int N, int K) {
  __shared__ u16 As[128 * 32];
  __shared__ u16 Bs[128 * 32];
  const int tid  = threadIdx.x;
  const int lane = tid & 63;
  const int wave = tid >> 6;
  const int wm = (wave >> 1) * 64;
  const int wn = (wave & 1) * 64;
  const long row0 = (long)blockIdx.x * 128;
  const long col0 = (long)blockIdx.y * 128;
  const int srow = tid >> 2;
  const int scol = (tid & 3) * 8;
  const u16* aptr = A + (row0 + srow) * (size_t)K + scol;
  const u16* bptr = B + (col0 + srow) * (size_t)K + scol;
  u16* asd  = &As[tid * 8];
  u16* asd2 = &As[2048 + tid * 8];
  u16* bsd  = &Bs[tid * 8];
  u16* bsd2 = &Bs[2048 + tid * 8];
  const int mrow = lane & 15;
  const int kq = (lane >> 4) * 8;
  f32x4 acc[4][4] = {};
  for (int k0 = 0; k0 < K; k0 += 32) {
    async_lds16(aptr, asd);
    async_lds16(aptr + (size_t)64 * K, asd2);
    async_lds16(bptr, bsd);
    async_lds16(bptr + (size_t)64 * K, bsd2);
    aptr += 32; bptr += 32;
    __syncthreads();   // drains vmcnt -> staged data visible
    short8 af[4], bfr[4];
#pragma unroll
    for (int i = 0; i < 4; ++i)
      af[i] = *(const short8*)(&As[(wm + i * 16 + mrow) * 32 + kq]);
#pragma unroll
    for (int j = 0; j < 4; ++j)
      bfr[j] = *(const short8*)(&Bs[(wn + j * 16 + mrow) * 32 + kq]);
#pragma unroll
    for (int i = 0; i < 4; ++i)
#pragma unroll
      for (int j = 0; j < 4; ++j)
        acc[i][j] = __builtin_amdgcn_mfma_f32_16x16x32_bf16(af[i], bfr[j], acc[i][j], 0, 0, 0);
    __syncthreads();   // all ds_reads done before next staging overwrites
  }
  const int cn = lane & 15;
  const int rq = (lane >> 4) * 4;
#pragma unroll
  for (int i = 0; i < 4; ++i)
#pragma unroll
    for (int j = 0; j < 4; ++j) {
      size_t r = (size_t)(row0 + wm + i * 16 + rq);
      size_t c = (size_t)(col0 + wn + j * 16 + cn);
#pragma unroll
      for (int rr = 0; rr < 4; ++rr) {
        if constexpr (BF16OUT)
          ((u16*)Cout)[(r + rr) * N + c] = f2bf(acc[i][j][rr]);
        else
          ((float*)Cout)[(r + rr) * N + c] = acc[i][j][rr];
      }
    }
}

// ---------------- conv(4-tap causal) + silu + l2norm + decay + beta --------
// one wave per (b,t,h); lane handles channels 2*lane, 2*lane+1
__global__ __launch_bounds__(256) void convprep(
    const u16* __restrict__ qraw, const u16* __restrict__ kraw,
    const u16* __restrict__ vraw, const u16* __restrict__ graw,
    const float* __restrict__ braw,
    const float* __restrict__ qcw, const float* __restrict__ kcw,
    const float* __restrict__ vcw, const float* __restrict__ A_log,
    const float* __restrict__ dt_bias,
    float* __restrict__ qc, float* __restrict__ kc, float* __restrict__ vc,
    float* __restrict__ dec, float* __restrict__ beta) {
  const int wid  = blockIdx.x * 4 + (threadIdx.x >> 6);
  const int lane = threadIdx.x & 63;
  const int h  = wid & 15;
  const int bt = wid >> 4;        // b*T + t
  const int t  = bt & (kT - 1);
  const int b  = bt >> 11;
  const int c0 = lane * 2;
  const size_t colofs = (size_t)h * kK + c0;
  const size_t rowb = (size_t)bt * kHK + colofs;
  const float* wq = qcw + colofs * 4;
  const float* wk = kcw + colofs * 4;
  const float* wv = vcw + colofs * 4;
  float qa0 = 0, qa1 = 0, ka0 = 0, ka1 = 0, va0 = 0, va1 = 0;
#pragma unroll
  for (int i = 0; i < 4; ++i) {       // tap i multiplies x[t-3+i]
    int tt = t - 3 + i;
    if (tt >= 0) {
      size_t ro = rowb - (size_t)(3 - i) * kHK;
      u32 uq = *(const u32*)(qraw + ro);
      u32 uk = *(const u32*)(kraw + ro);
      u32 uv = *(const u32*)(vraw + ro);
      qa0 += bflo(uq) * wq[i];  qa1 += bfhi(uq) * wq[4 + i];
      ka0 += bflo(uk) * wk[i];  ka1 += bfhi(uk) * wk[4 + i];
      va0 += bflo(uv) * wv[i];  va1 += bfhi(uv) * wv[4 + i];
    }
  }
  qa0 *= sigmoidf(qa0); qa1 *= sigmoidf(qa1);
  ka0 *= sigmoidf(ka0); ka1 *= sigmoidf(ka1);
  va0 *= sigmoidf(va0); va1 *= sigmoidf(va1);
  float sq = qa0 * qa0 + qa1 * qa1;
  float sk = ka0 * ka0 + ka1 * ka1;
#pragma unroll
  for (int m = 1; m < 64; m <<= 1) {
    sq += __shfl_xor(sq, m);
    sk += __shfl_xor(sk, m);
  }
  float qinv = 1.0f / fmaxf(sqrtf(sq), 1e-12f);
  float kinv = 1.0f / fmaxf(sqrtf(sk), 1e-12f);
  const size_t outb = ((size_t)(b * kH + h) * kT + t) * kK + c0;
  *(float2*)(qc + outb) = make_float2(qa0 * qinv, qa1 * qinv);
  *(float2*)(kc + outb) = make_float2(ka0 * kinv, ka1 * kinv);
  *(float2*)(vc + outb) = make_float2(va0, va1);
  // decay = exp(-exp(A_log)*softplus(g_raw + dt_bias))
  u32 ug = *(const u32*)(graw + rowb);
  float Ae = expf(A_log[h]);
  float g0 = bflo(ug) + dt_bias[colofs];
  float g1 = bfhi(ug) + dt_bias[colofs + 1];
  float sp0 = (g0 > 15.f) ? g0 : log1pf(expf(g0));
  float sp1 = (g1 > 15.f) ? g1 : log1pf(expf(g1));
  *(float2*)(dec + outb) = make_float2(expf(-Ae * sp0), expf(-Ae * sp1));
  if (lane == 0) {
    float bv = braw[(size_t)bt * 128 + h];
    beta[(size_t)(b * kH + h) * kT + t] = sigmoidf(bv);
  }
}

// ---------------- KDA delta-rule scan (LDS chunk-staged, double-buffered) --
// grid: 256 blocks of 4 waves. block -> (bh = blk>>3, vgroup base (blk&7)*4).
// wave w handles v-cols [ (vgBase+w)*4 .. +4 ); lane = kg*4+vcl, kg in [0,16)
// holds 8 k-rows of state. o-reduction deferred one iteration off the
// critical path (its 4 shfls overlap the next step's decay-mul/dot-tree).
constexpr int kC = 16;   // chunk length (timesteps per stage)

__global__ __launch_bounds__(256) void kda_scan(
    const float* __restrict__ qc, const float* __restrict__ kc,
    const float* __restrict__ vcp, const float* __restrict__ dec,
    const float* __restrict__ betap, float* __restrict__ yf) {
  __shared__ float qsh[2][kC][kK];
  __shared__ float ksh[2][kC][kK];
  __shared__ float dsh[2][kC][kK];
  __shared__ float vsh[2][kC][16];
  __shared__ float bsh[2][kC];
  const int tid  = threadIdx.x;
  const int lane = tid & 63;
  const int w    = tid >> 6;
  const int bh     = blockIdx.x >> 3;
  const int vgBase = (blockIdx.x & 7) * 4;
  const int vcl = lane & 3;
  const int kg  = lane >> 2;
  const int vi  = (vgBase + w) * 4 + vcl;   // this lane's v-column
  const int cb  = vgBase * 4;               // block's first v-column (16 wide)
  const float* qb = qc  + (size_t)bh * kT * kK;
  const float* kb = kc  + (size_t)bh * kT * kK;
  const float* db = dec + (size_t)bh * kT * kK;
  const float* vb = vcp + (size_t)bh * kT * kV;
  const float* bp = betap + (size_t)bh * kT;
  float* yb = yf + (size_t)bh * kT * kV;

  auto stage = [&](int buf, int t0) {
    const size_t go = (size_t)t0 * kK;   // float offset of chunk start
#pragma unroll
    for (int i = 0; i < 2; ++i) {
      int ofs = (i * 256 + tid) * 4;     // float index within 8KB chunk
      async_lds16(qb + go + ofs, &qsh[buf][0][0] + ofs);
      async_lds16(kb + go + ofs, &ksh[buf][0][0] + ofs);
      async_lds16(db + go + ofs, &dsh[buf][0][0] + ofs);
    }
    {
      int t = tid >> 4, c = tid & 15;
      vsh[buf][t][c] = vb[(size_t)(t0 + t) * kV + cb + c];
    }
    if (tid < kC) bsh[buf][tid] = bp[t0 + tid];
  };

  stage(0, 0);
  float S0 = 0, S1 = 0, S2 = 0, S3 = 0, S4 = 0, S5 = 0, S6 = 0, S7 = 0;
  float oprev = 0.f;
  int tprev = -1;
  for (int ch = 0; ch < kT / kC; ++ch) {
    const int cur = ch & 1;
    __syncthreads();                       // staged chunk `cur` is ready
    if (ch + 1 < kT / kC) stage(cur ^ 1, (ch + 1) * kC);
#pragma unroll 4
    for (int tt = 0; tt < kC; ++tt) {
      float4 kk0 = *(const float4*)&ksh[cur][tt][kg * 8];
      float4 kk1 = *(const float4*)&ksh[cur][tt][kg * 8 + 4];
      float4 d0  = *(const float4*)&dsh[cur][tt][kg * 8];
      float4 d1  = *(const float4*)&dsh[cur][tt][kg * 8 + 4];
      float4 q0  = *(const float4*)&qsh[cur][tt][kg * 8];
      float4 q1  = *(const float4*)&qsh[cur][tt][kg * 8 + 4];
      float vt = vsh[cur][tt][w * 4 + vcl];
      float bt = bsh[cur][tt];
      // finish previous step's output reduction (off the S critical path)
      {
        float o = oprev;
        o += __shfl_xor(o, 4);
        o += __shfl_xor(o, 8);
        o += __shfl_xor(o, 16);
        o += __shfl_xor(o, 32);
        if (tprev >= 0 && kg == 0) yb[(size_t)tprev * kV + vi] = o;
      }
      // S' = decay*S ; err = v - k.S' ; S = S' + beta*err*k
      float t0 = d0.x * S0, t1 = d0.y * S1, t2 = d0.z * S2, t3 = d0.w * S3;
      float t4 = d1.x * S4, t5 = d1.y * S5, t6 = d1.z * S6, t7 = d1.w * S7;
      float dot = ((kk0.x * t0 + kk0.y * t1) + (kk0.z * t2 + kk0.w * t3)) +
                  ((kk1.x * t4 + kk1.y * t5) + (kk1.z * t6 + kk1.w * t7));
      dot += __shfl_xor(dot, 4);
      dot += __shfl_xor(dot, 8);
      dot += __shfl_xor(dot, 16);
      dot += __shfl_xor(dot, 32);
      float u = bt * (vt - dot);
      S0 = fmaf(u, kk0.x, t0); S1 = fmaf(u, kk0.y, t1);
      S2 = fmaf(u, kk0.z, t2); S3 = fmaf(u, kk0.w, t3);
      S4 = fmaf(u, kk1.x, t4); S5 = fmaf(u, kk1.y, t5);
      S6 = fmaf(u, kk1.z, t6); S7 = fmaf(u, kk1.w, t7);
      // partial output (reduced next iteration)
      oprev = ((q0.x * S0 + q0.y * S1) + (q0.z * S2 + q0.w * S3)) +
              ((q1.x * S4 + q1.y * S5) + (q1.z * S6 + q1.w * S7));
      tprev = ch * kC + tt;
    }
  }
  // final step's output
  {
    float o = oprev;
    o += __shfl_xor(o, 4);
    o += __shfl_xor(o, 8);
    o += __shfl_xor(o, 16);
    o += __shfl_xor(o, 32);
    if (kg == 0) yb[(size_t)tprev * kV + vi] = o;
  }
}

// ---------------- rmsnorm * o_norm_w * sigmoid(gate+bg) -> bf16 -----------
__global__ __launch_bounds__(256) void postk(
    const float* __restrict__ yf, const u16* __restrict__ gateb,
    const float* __restrict__ bg, const float* __restrict__ onw,
    u16* __restrict__ ygb) {
  const int wid  = blockIdx.x * 4 + (threadIdx.x >> 6);
  const int lane = threadIdx.x & 63;
  const int h  = wid & 15;
  const int bt = wid >> 4;
  const int t  = bt & (kT - 1);
  const int b  = bt >> 11;
  const int v0 = lane * 2;
  const size_t yi = ((size_t)(b * kH + h) * kT + t) * kV + v0;
  float2 yv = *(const float2*)(yf + yi);
  float s = yv.x * yv.x + yv.y * yv.y;
#pragma unroll
  for (int m = 1; m < 64; m <<= 1) s += __shfl_xor(s, m);
  float scale = rsqrtf(s * (1.0f / 128.0f) + 1.1920929e-07f);
  const size_t gi = (size_t)bt * kHV + (size_t)h * kV + v0;
  u32 ug = *(const u32*)(gateb + gi);
  float g0 = bflo(ug) + bg[h * kV + v0];
  float g1 = bfhi(ug) + bg[h * kV + v0 + 1];
  float r0 = yv.x * scale * onw[v0] * sigmoidf(g0);
  float r1 = yv.y * scale * onw[v0 + 1] * sigmoidf(g1);
  *(u32*)(ygb + gi) = (u32)f2bf(r0) | ((u32)f2bf(r1) << 16);
}

// ---------------- host launcher ----------------
extern "C" void kernel_launch(void* const* d_in, const int* in_sizes, int n_in,
                              void* d_out, int out_size, void* d_ws, size_t ws_size,
                              hipStream_t stream) {
  (void)in_sizes; (void)n_in; (void)out_size; (void)ws_size;
  const float* x    = (const float*)d_in[0];
  const float* Wq   = (const float*)d_in[1];
  const float* Wk   = (const float*)d_in[2];
  const float* Wv   = (const float*)d_in[3];
  const float* Wf1  = (const float*)d_in[4];
  const float* Wf2  = (const float*)d_in[5];
  const float* Wb   = (const float*)d_in[6];
  const float* Wg1  = (const float*)d_in[7];
  const float* Wg2  = (const float*)d_in[8];
  const float* bg   = (const float*)d_in[9];
  const float* onw  = (const float*)d_in[10];
  const float* Wout = (const float*)d_in[11];
  const float* A_log   = (const float*)d_in[12];
  const float* dt_bias = (const float*)d_in[13];
  const float* qcw  = (const float*)d_in[14];
  const float* kcw  = (const float*)d_in[15];
  const float* vcw  = (const float*)d_in[16];

  char* ws = (char*)d_ws;
  u16* xb    = (u16*)(ws + OFF_XB);
  u16* Wqb   = (u16*)(ws + OFF_WQB);
  u16* Wkb   = (u16*)(ws + OFF_WKB);
  u16* Wvb   = (u16*)(ws + OFF_WVB);
  u16* Wf1b  = (u16*)(ws + OFF_WF1B);
  u16* Wg1b  = (u16*)(ws + OFF_WG1B);
  u16* Wf2b  = (u16*)(ws + OFF_WF2B);
  u16* Wg2b  = (u16*)(ws + OFF_WG2B);
  u16* Wbp   = (u16*)(ws + OFF_WBP);
  u16* Woutb = (u16*)(ws + OFF_WOUTB);
  u16* qraw  = (u16*)(ws + OFF_QRAW);
  u16* kraw  = (u16*)(ws + OFF_KRAW);
  u16* vraw  = (u16*)(ws + OFF_VRAW);
  u16* graw  = (u16*)(ws + OFF_GRAW);
  u16* gateb = (u16*)(ws + OFF_GATEB);
  u16* f1b   = (u16*)(ws + OFF_F1B);
  u16* g1b   = (u16*)(ws + OFF_G1B);
  u16* ygb   = (u16*)(ws + OFF_YGB);
  float* brawf = (float*)(ws + OFF_BRAW);
  float* qcf   = (float*)(ws + OFF_QC);
  float* kcf   = (float*)(ws + OFF_KC);
  float* vcf   = (float*)(ws + OFF_VC);
  float* decf  = (float*)(ws + OFF_DEC);
  float* betaf = (float*)(ws + OFF_BETA);
  float* yff   = (float*)(ws + OFF_YF);

  auto cast = [&](const float* src, u16* dst, int n) {
    cast_bf16<<<(n / 4 + 255) / 256, 256, 0, stream>>>(src, dst, n);
  };
  cast(x, xb, kM * kD);
  cast(Wq, Wqb, kHK * kD);
  cast(Wk, Wkb, kHK * kD);
  cast(Wv, Wvb, kHV * kD);
  cast(Wout, Woutb, kD * kHV);
  cast(Wf1, Wf1b, kV * kD);
  cast(Wg1, Wg1b, kV * kD);
  cast(Wf2, Wf2b, kHK * kV);
  cast(Wg2, Wg2b, kHV * kV);
  pad_wb<<<(128 * 2048 / 4 + 255) / 256, 256, 0, stream>>>(Wb, Wbp);

  dim3 blk(256);
  gemm_bt<true><<<dim3(kM / 128, kHK / 128), blk, 0, stream>>>(xb, Wqb, qraw, kM, kHK, kD);
  gemm_bt<true><<<dim3(kM / 128, kHK / 128), blk, 0, stream>>>(xb, Wkb, kraw, kM, kHK, kD);
  gemm_bt<true><<<dim3(kM / 128, kHV / 128), blk, 0, stream>>>(xb, Wvb, vraw, kM, kHV, kD);
  gemm_bt<true><<<dim3(kM / 128, 1), blk, 0, stream>>>(xb, Wf1b, f1b, kM, 128, kD);
  gemm_bt<true><<<dim3(kM / 128, 1), blk, 0, stream>>>(xb, Wg1b, g1b, kM, 128, kD);
  gemm_bt<false><<<dim3(kM / 128, 1), blk, 0, stream>>>(xb, Wbp, brawf, kM, 128, kD);
  gemm_bt<true><<<dim3(kM / 128, kHK / 128), blk, 0, stream>>>(f1b, Wf2b, graw, kM, kHK, kV);
  gemm_bt<true><<<dim3(kM / 128, kHV / 128), blk, 0, stream>>>(g1b, Wg2b, gateb, kM, kHV, kV);

  convprep<<<kB * kT * kH / 4, 256, 0, stream>>>(qraw, kraw, vraw, graw, brawf,
                                                 qcw, kcw, vcw, A_log, dt_bias,
                                                 qcf, kcf, vcf, decf, betaf);

  kda_scan<<<256, 256, 0, stream>>>(qcf, kcf, vcf, decf, betaf, yff);

  postk<<<kB * kT * kH / 4, 256, 0, stream>>>(yff, gateb, bg, onw, ygb);

  gemm_bt<false><<<dim3(kM / 128, kD / 128), blk, 0, stream>>>(ygb, Woutb, (float*)d_out, kM, kD, kHV);
}